// Round 5
// baseline (371.439 us; speedup 1.0000x reference)
//
#include <hip/hip_runtime.h>
#include <math.h>

// Problem constants: B=4, S=2048, D=512, H=8, Hd=64
#define SEQ 2048
#define DM 512
#define NH 8
#define HD 64

typedef __bf16 bf16x8 __attribute__((ext_vector_type(8)));
typedef __bf16 bf16x4 __attribute__((ext_vector_type(4)));
typedef __bf16 bf16x2 __attribute__((ext_vector_type(2)));
typedef float f32x4 __attribute__((ext_vector_type(4)));
#define MFMA16(A, B, C) __builtin_amdgcn_mfma_f32_16x16x32_bf16(A, B, C, 0, 0, 0)

__device__ __forceinline__ void async16(const void* g, void* l) {
    __builtin_amdgcn_global_load_lds((__attribute__((address_space(1))) void*)g,
                                     (__attribute__((address_space(3))) void*)l,
                                     16, 0, 0);
}
#define LGKM0() asm volatile("s_waitcnt lgkmcnt(0)" ::: "memory")
#define VMCNT0() asm volatile("s_waitcnt vmcnt(0)" ::: "memory")

// scale = 1/sqrt(64) * log2(e), folded into q at the QKV epilogue
#define QSCALE 0.18033688011112042f

// ---------------------------------------------------------------------------
// Prep 1: RoPE table  tab[s][p] = (cos, sin)(s * 10000^(-p/32)), 2048x32
// ---------------------------------------------------------------------------
__global__ __launch_bounds__(256)
void prep_rope(float2* __restrict__ tab)
{
    int idx = blockIdx.x * 256 + threadIdx.x;   // 65536
    int s = idx >> 5, p = idx & 31;
    const float c = -0.28782313662425572f;      // -ln(10000)/32
    float f = (float)s * expf(c * (float)p);
    float sn, cs;
    sincosf(f, &sn, &cs);
    tab[idx] = make_float2(cs, sn);
}

// ---------------------------------------------------------------------------
// Prep 2: W [512][N] fp32 -> Wt hi/lo bf16 [N][512], via LDS tile transpose
// (coalesced reads AND writes; old version did 2B scattered stores).
// grid (N/64, 512/64), block 256.
// ---------------------------------------------------------------------------
__global__ __launch_bounds__(256)
void prep_tw(const float* __restrict__ W, __bf16* __restrict__ hi,
             __bf16* __restrict__ lo, int N)
{
    __shared__ float T[64][65];
    const int tid = threadIdx.x;
    const int c0 = blockIdx.x * 64, k0 = blockIdx.y * 64;
#pragma unroll
    for (int it = 0; it < 4; ++it) {
        int idx = it * 256 + tid;
        int r = idx >> 4, c4 = (idx & 15) << 2;
        *(float4*)&T[r][c4] = *(const float4*)&W[(size_t)(k0 + r) * N + c0 + c4];
    }
    __syncthreads();
#pragma unroll
    for (int it = 0; it < 4; ++it) {
        int idx = it * 256 + tid;
        int c = idx >> 4, k4 = (idx & 15) << 2;
        bf16x4 hv, lv;
#pragma unroll
        for (int r = 0; r < 4; ++r) {
            float w = T[k4 + r][c];
            __bf16 h = (__bf16)w;
            hv[r] = h;
            lv[r] = (__bf16)(w - (float)h);
        }
        size_t off = (size_t)(c0 + c) * DM + k0 + k4;
        *(bf16x4*)&hi[off] = hv;
        *(bf16x4*)&lo[off] = lv;
    }
}

// ---------------------------------------------------------------------------
// Prep 3: x fp32 -> xhi/xlo bf16 (row-major [8192][512])
// ---------------------------------------------------------------------------
__global__ __launch_bounds__(256)
void prep_x(const float* __restrict__ x, __bf16* __restrict__ xh,
            __bf16* __restrict__ xl)
{
    size_t i = ((size_t)blockIdx.x * 256 + threadIdx.x) << 3;
    float4 a0 = *(const float4*)&x[i];
    float4 a1 = *(const float4*)&x[i + 4];
    float fv[8] = {a0.x, a0.y, a0.z, a0.w, a1.x, a1.y, a1.z, a1.w};
    bf16x8 hv, lv;
#pragma unroll
    for (int j = 0; j < 8; ++j) {
        __bf16 h = (__bf16)fv[j];
        hv[j] = h;
        lv[j] = (__bf16)(fv[j] - (float)h);
    }
    *(bf16x8*)&xh[i] = hv;
    *(bf16x8*)&xl[i] = lv;
}

// ---------------------------------------------------------------------------
// Kernel 1: QKV GEMM, async-staged split-bf16 MFMA (128x128, 4 waves).
// Epilogue: LDS transpose -> bias + RoPE -> vector stores.
// q: PRE-SCALED (QSCALE) hi/lo bf16 [B,H,S,64]; k: hi/lo bf16 [B,H,S,64];
// v: bf16 transposed [B,H,64,S].
// ---------------------------------------------------------------------------
__global__ __launch_bounds__(256)
void qkv_mfma(const __bf16* __restrict__ xh, const __bf16* __restrict__ xl,
              const __bf16* __restrict__ wth, const __bf16* __restrict__ wtl,
              const float* __restrict__ bias, const float2* __restrict__ tab,
              __bf16* __restrict__ qho, __bf16* __restrict__ qlo_,
              __bf16* __restrict__ kho, __bf16* __restrict__ klo_,
              __bf16* __restrict__ vo)
{
    __shared__ __align__(16) __bf16 SM[16384];      // 32 KB
    __bf16* Ah = SM;
    __bf16* Al = SM + 4096;
    __bf16* Bh = SM + 8192;
    __bf16* Bl = SM + 12288;

    const int tid  = threadIdx.x;
    const int lane = tid & 63;
    const int wave = tid >> 6;
    const int quad = lane >> 4;
    const int m    = lane & 15;
    const int wr   = wave >> 1, wc = wave & 1;
    const int row0 = blockIdx.x * 128;
    const int by   = blockIdx.y;            // 0..11
    const int col0 = by * 128;

    const size_t aoff0 = (size_t)(row0 + wave * 16 + m) * DM + (quad << 3);
    const size_t aoff1 = (size_t)(row0 + (wave + 4) * 16 + m) * DM + (quad << 3);
    const size_t boff0 = (size_t)(col0 + wave * 16 + m) * DM + (quad << 3);
    const size_t boff1 = (size_t)(col0 + (wave + 4) * 16 + m) * DM + (quad << 3);
    __bf16* lA0 = &Ah[wave << 9];       __bf16* lA1 = &Ah[(wave + 4) << 9];
    __bf16* lAl0 = &Al[wave << 9];      __bf16* lAl1 = &Al[(wave + 4) << 9];
    __bf16* lB0 = &Bh[wave << 9];       __bf16* lB1 = &Bh[(wave + 4) << 9];
    __bf16* lBl0 = &Bl[wave << 9];      __bf16* lBl1 = &Bl[(wave + 4) << 9];

    f32x4 acc[4][4];
#pragma unroll
    for (int i = 0; i < 4; ++i)
#pragma unroll
        for (int j = 0; j < 4; ++j) acc[i][j] = (f32x4){0.f, 0.f, 0.f, 0.f};

    for (int k0 = 0; k0 < DM; k0 += 32) {
        async16(xh + aoff0 + k0, lA0);
        async16(xh + aoff1 + k0, lA1);
        async16(xl + aoff0 + k0, lAl0);
        async16(xl + aoff1 + k0, lAl1);
        async16(wth + boff0 + k0, lB0);
        async16(wth + boff1 + k0, lB1);
        async16(wtl + boff0 + k0, lBl0);
        async16(wtl + boff1 + k0, lBl1);
        __syncthreads();

        bf16x8 avh[4], avl[4], bvh[4], bvl[4];
#pragma unroll
        for (int t = 0; t < 4; ++t) {
            int ai  = ((((wr << 2) + t) << 6) + lane) << 3;
            int bi2 = ((((wc << 2) + t) << 6) + lane) << 3;
            avh[t] = *(const bf16x8*)&Ah[ai];
            avl[t] = *(const bf16x8*)&Al[ai];
            bvh[t] = *(const bf16x8*)&Bh[bi2];
            bvl[t] = *(const bf16x8*)&Bl[bi2];
        }
#pragma unroll
        for (int rt = 0; rt < 4; ++rt)
#pragma unroll
            for (int ct = 0; ct < 4; ++ct) {
                acc[rt][ct] = MFMA16(avh[rt], bvl[ct], acc[rt][ct]);
                acc[rt][ct] = MFMA16(avl[rt], bvh[ct], acc[rt][ct]);
                acc[rt][ct] = MFMA16(avh[rt], bvh[ct], acc[rt][ct]);
            }
        __syncthreads();
    }

    // ---- epilogue ----
    const int sel   = by >> 2;              // 0=q 1=k 2=v
    const int head  = ((by << 1) + wc) & 7;
    const int row0w = row0 + wr * 64;
    const int bidx  = row0w >> 11;
    const int s0    = row0w & (SEQ - 1);
    const int colw  = col0 + wc * 64;

    float bc[4];
#pragma unroll
    for (int ct = 0; ct < 4; ++ct) bc[ct] = bias[colw + (ct << 4) + m];

    if (sel == 2) {
        // v: direct transposed store [B,H,d,s], bf16x4 along s
#pragma unroll
        for (int ct = 0; ct < 4; ++ct) {
            int d = (ct << 4) + m;
#pragma unroll
            for (int rt = 0; rt < 4; ++rt) {
                f32x4 a = acc[rt][ct];
                bf16x4 ov;
#pragma unroll
                for (int rg = 0; rg < 4; ++rg) ov[rg] = (__bf16)(a[rg] + bc[ct]);
                size_t off = ((size_t)((bidx * NH + head) * HD + d)) * SEQ
                           + s0 + (rt << 4) + (quad << 2);
                *(bf16x4*)&vo[off] = ov;
            }
        }
    } else {
        // q/k: per-wave LDS transpose + RoPE + hi/lo bf16 vector stores
        const float sc = (sel == 0) ? QSCALE : 1.0f;
        __bf16* dh = (sel == 0) ? qho : kho;
        __bf16* dl = (sel == 0) ? qlo_ : klo_;
        float* tb = (float*)SM + wave * 1088;       // 16 x 68 f32
        const int rr = lane >> 2, jj = lane & 3;
#pragma unroll
        for (int rt = 0; rt < 4; ++rt) {
#pragma unroll
            for (int ct = 0; ct < 4; ++ct)
#pragma unroll
                for (int rg = 0; rg < 4; ++rg)
                    tb[((quad << 2) + rg) * 68 + (ct << 4) + m] =
                        acc[rt][ct][rg] + bc[ct];
            LGKM0();
            int s = (row0w + (rt << 4) + rr) & (SEQ - 1);
#pragma unroll
            for (int i = 0; i < 4; ++i) {
                int c = (jj << 2) + (i << 4);
                float4 vv = *(const float4*)&tb[rr * 68 + c];
                float4 t4 = *(const float4*)&tab[(s << 5) + (c >> 1)];
                float rv[4];
                rv[0] = (vv.x * t4.x - vv.y * t4.y) * sc;
                rv[1] = (vv.x * t4.y + vv.y * t4.x) * sc;
                rv[2] = (vv.z * t4.z - vv.w * t4.w) * sc;
                rv[3] = (vv.z * t4.w + vv.w * t4.z) * sc;
                size_t off = (((size_t)(bidx * NH + head) * SEQ + s) << 6) + c;
                bf16x4 hv, lv;
#pragma unroll
                for (int j = 0; j < 4; ++j) {
                    __bf16 h = (__bf16)rv[j];
                    hv[j] = h;
                    lv[j] = (__bf16)(rv[j] - (float)h);
                }
                *(bf16x4*)&dh[off] = hv;
                *(bf16x4*)&dl[off] = lv;
            }
        }
    }
}

// ---------------------------------------------------------------------------
// Kernel 2: barrier-free key-split MFMA flash attention.
// Block = (qt, bh): 64 q-rows. Wave w owns keys [w*512, w*512+512), iterated
// in 16 chunks of 32, staged into wave-PRIVATE LDS via global_load_lds with
// vmcnt-only waits (no __syncthreads in the loop) + next-chunk prefetch.
// S^T = K·Q^T (Q persistent B-frags, 64 q per wave); O^T = V^T·P^T so the
// softmax state is per-lane; P C->B-frag transform done with register shfl.
// Per-wave (m,l,O) merged once at the end via LDS atomics.
// Output written pre-split hi/lo bf16 [B,S,512] for the out GEMM.
// ---------------------------------------------------------------------------
__global__ __launch_bounds__(256, 2)
void attn_mfma(const __bf16* __restrict__ qhi, const __bf16* __restrict__ qlo,
               const __bf16* __restrict__ khi, const __bf16* __restrict__ klo,
               const __bf16* __restrict__ vt,
               __bf16* __restrict__ oh, __bf16* __restrict__ ol)
{
    __shared__ __align__(16) __bf16 SM[24576];   // 48 KB: 4 waves x 12 KB
    const int tid  = threadIdx.x;
    const int lane = tid & 63;
    const int wave = tid >> 6;
    const int m    = lane & 15;
    const int quad = lane >> 4;

    const int bh = blockIdx.y;      // 0..31
    const int qt = blockIdx.x;      // 0..31
    const int bi = bh >> 3, h = bh & 7;

    const __bf16* qhp = qhi + ((size_t)bh * SEQ + qt * 64) * HD;
    const __bf16* qlp = qlo + ((size_t)bh * SEQ + qt * 64) * HD;
    const __bf16* khp = khi + (size_t)bh * SEQ * HD;
    const __bf16* klp = klo + (size_t)bh * SEQ * HD;
    const __bf16* vp  = vt  + (size_t)bh * HD * SEQ;

    __bf16* KHw = SM + wave * 6144;     // [kg2][c2][lane][8]
    __bf16* KLw = KHw + 2048;
    __bf16* VFw = KHw + 4096;           // [dg4][lane][8]

    // Q B-frags (pre-scaled at QKV): B[k=d][n=q], element [c*32+quad*8+j][qg*16+m]
    bf16x8 qh[4][2], ql[4][2];
#pragma unroll
    for (int qg = 0; qg < 4; ++qg)
#pragma unroll
        for (int c = 0; c < 2; ++c) {
            size_t off = ((size_t)(qg * 16 + m) << 6) + c * 32 + (quad << 3);
            qh[qg][c] = *(const bf16x8*)&qhp[off];
            ql[qg][c] = *(const bf16x8*)&qlp[off];
        }

    f32x4 oacc[4][4];   // O^T tile [dg][qg]: row d=quad*4+rg(+16dg), col q=m(+16qg)
#pragma unroll
    for (int dg = 0; dg < 4; ++dg)
#pragma unroll
        for (int qg = 0; qg < 4; ++qg) oacc[dg][qg] = (f32x4){0.f, 0.f, 0.f, 0.f};
    float mrow[4] = {-1e30f, -1e30f, -1e30f, -1e30f};
    float lrow[4] = {0.f, 0.f, 0.f, 0.f};

    const int kb0 = wave * 512;
    auto stage = [&](int kbase) {
#pragma unroll
        for (int kg = 0; kg < 2; ++kg)
#pragma unroll
            for (int c = 0; c < 2; ++c) {
                size_t so = ((size_t)(kbase + kg * 16 + m) << 6) + c * 32 + (quad << 3);
                async16(khp + so, KHw + ((kg << 1) + c) * 512);
                async16(klp + so, KLw + ((kg << 1) + c) * 512);
            }
#pragma unroll
        for (int dg = 0; dg < 4; ++dg)
            async16(vp + ((size_t)(dg * 16 + m) << 11) + kbase + (quad << 3),
                    VFw + dg * 512);
    };
    stage(kb0);

    union PU { int i; bf16x2 v; };
    union PF { bf16x8 v; int d[4]; };
    const int sb = m + ((quad & 1) << 5);   // shfl src base: m + 32*(quad&1)
    const bool hiKg = (quad >= 2);

    for (int j = 0; j < 16; ++j) {
        VMCNT0();   // chunk j staged (wave-private, no barrier)
        bf16x8 kfh[2][2], kfl[2][2], vf[4];
#pragma unroll
        for (int kg = 0; kg < 2; ++kg)
#pragma unroll
            for (int c = 0; c < 2; ++c) {
                int o = ((((kg << 1) + c) << 6) + lane) << 3;
                kfh[kg][c] = *(const bf16x8*)&KHw[o];
                kfl[kg][c] = *(const bf16x8*)&KLw[o];
            }
#pragma unroll
        for (int dg = 0; dg < 4; ++dg)
            vf[dg] = *(const bf16x8*)&VFw[((dg << 6) + lane) << 3];
        LGKM0();    // frags in regs; safe to overwrite LDS
        if (j < 15) stage(kb0 + (j + 1) * 32);

        // ---- S^T = K·Q^T : [32 keys][64 q], 3-term split ----
        f32x4 sv[2][4];
#pragma unroll
        for (int kg = 0; kg < 2; ++kg)
#pragma unroll
            for (int qg = 0; qg < 4; ++qg) {
                f32x4 s = (f32x4){0.f, 0.f, 0.f, 0.f};
#pragma unroll
                for (int c = 0; c < 2; ++c) {
                    s = MFMA16(kfh[kg][c], ql[qg][c], s);
                    s = MFMA16(kfl[kg][c], qh[qg][c], s);
                    s = MFMA16(kfh[kg][c], qh[qg][c], s);
                }
                sv[kg][qg] = s;   // [key=kg*16+quad*4+rg][q=qg*16+m]
            }

        // ---- online softmax (per-lane q=qg*16+m), log2 domain ----
        float mn[4], alpha[4];
        int nc = 1;
#pragma unroll
        for (int qg = 0; qg < 4; ++qg) {
            f32x4 a = sv[0][qg], b = sv[1][qg];
            float t = fmaxf(fmaxf(fmaxf(a[0], a[1]), fmaxf(a[2], a[3])),
                            fmaxf(fmaxf(b[0], b[1]), fmaxf(b[2], b[3])));
            t = fmaxf(t, __shfl_xor(t, 16));
            t = fmaxf(t, __shfl_xor(t, 32));
            float mo = mrow[qg];
            mn[qg] = fmaxf(mo, t);
            nc &= (mn[qg] == mo) ? 1 : 0;
            alpha[qg] = exp2f(mo - mn[qg]);
            mrow[qg] = mn[qg];
        }
#pragma unroll
        for (int qg = 0; qg < 4; ++qg) {
            float rs = 0.f;
#pragma unroll
            for (int kg = 0; kg < 2; ++kg)
#pragma unroll
                for (int rg = 0; rg < 4; ++rg) {
                    float p = exp2f(sv[kg][qg][rg] - mn[qg]);
                    sv[kg][qg][rg] = p;
                    rs += p;
                }
            rs += __shfl_xor(rs, 16);
            rs += __shfl_xor(rs, 32);
            lrow[qg] = lrow[qg] * alpha[qg] + rs;
        }
        if (!__all(nc)) {
#pragma unroll
            for (int dg = 0; dg < 4; ++dg)
#pragma unroll
                for (int qg = 0; qg < 4; ++qg)
#pragma unroll
                    for (int rg = 0; rg < 4; ++rg)
                        oacc[dg][qg][rg] *= alpha[qg];
        }

        // ---- P: C-layout -> B-frag via register shfl (quad exchange) ----
        int prb[2][4][2];
#pragma unroll
        for (int kg = 0; kg < 2; ++kg)
#pragma unroll
            for (int qg = 0; qg < 4; ++qg)
#pragma unroll
                for (int pp = 0; pp < 2; ++pp) {
                    PU u;
                    u.v = (bf16x2){(__bf16)sv[kg][qg][2 * pp],
                                   (__bf16)sv[kg][qg][2 * pp + 1]};
                    prb[kg][qg][pp] = u.i;
                }
        bf16x8 pf[4];
#pragma unroll
        for (int qg = 0; qg < 4; ++qg) {
            PF u;
#pragma unroll
            for (int j2 = 0; j2 < 4; ++j2) {
                int src = sb + ((j2 >> 1) << 4);
                int v0 = __shfl(prb[0][qg][j2 & 1], src);
                int v1 = __shfl(prb[1][qg][j2 & 1], src);
                u.d[j2] = hiKg ? v1 : v0;
            }
            pf[qg] = u.v;
        }

        // ---- O^T += V^T · P^T ----
#pragma unroll
        for (int dg = 0; dg < 4; ++dg)
#pragma unroll
            for (int qg = 0; qg < 4; ++qg)
                oacc[dg][qg] = MFMA16(vf[dg], pf[qg], oacc[dg][qg]);
    }

    // ---- merge the 4 waves' partial (m, l, O) ----
    float* MB = (float*)SM;           // [4][64]
    float* LB = MB + 256;             // [4][64]
    float* OB = MB + 512;             // [64][67] fp32
    __syncthreads();                  // all waves done with staging LDS
    if (quad == 0) {
#pragma unroll
        for (int qg = 0; qg < 4; ++qg) {
            MB[wave * 64 + qg * 16 + m] = mrow[qg];
            LB[wave * 64 + qg * 16 + m] = lrow[qg];
        }
    }
    for (int i = tid; i < 64 * 67; i += 256) OB[i] = 0.f;
    __syncthreads();
    float fac[4];
#pragma unroll
    for (int qg = 0; qg < 4; ++qg) {
        int qq = qg * 16 + m;
        float m0 = MB[qq], m1 = MB[64 + qq], m2 = MB[128 + qq], m3 = MB[192 + qq];
        float ms = fmaxf(fmaxf(m0, m1), fmaxf(m2, m3));
        float ls = exp2f(m0 - ms) * LB[qq] + exp2f(m1 - ms) * LB[64 + qq] +
                   exp2f(m2 - ms) * LB[128 + qq] + exp2f(m3 - ms) * LB[192 + qq];
        fac[qg] = exp2f(mrow[qg] - ms) / ls;
    }
#pragma unroll
    for (int dg = 0; dg < 4; ++dg)
#pragma unroll
        for (int qg = 0; qg < 4; ++qg)
#pragma unroll
            for (int rg = 0; rg < 4; ++rg)
                atomicAdd(&OB[(dg * 16 + (quad << 2) + rg) * 67 + qg * 16 + m],
                          oacc[dg][qg][rg] * fac[qg]);
    __syncthreads();

    // ---- coalesced split store [B,S,H*64] ----
    const int qq = tid >> 2;
    size_t orow = ((size_t)(bi * SEQ + qt * 64 + qq)) * DM + h * HD;
#pragma unroll
    for (int i = 0; i < 4; ++i) {
        int d0 = ((tid & 3) << 2) + (i << 4);
        bf16x4 hv, lv;
#pragma unroll
        for (int r = 0; r < 4; ++r) {
            float v = OB[(d0 + r) * 67 + qq];
            __bf16 hb = (__bf16)v;
            hv[r] = hb;
            lv[r] = (__bf16)(v - (float)hb);
        }
        *(bf16x4*)&oh[orow + d0] = hv;
        *(bf16x4*)&ol[orow + d0] = lv;
    }
}

// ---------------------------------------------------------------------------
// Kernel 3: out = attn @ Wo + bo, async-staged split-bf16 MFMA (128x128).
// ---------------------------------------------------------------------------
__global__ __launch_bounds__(256)
void out_mfma(const __bf16* __restrict__ ah, const __bf16* __restrict__ al_,
              const __bf16* __restrict__ wth, const __bf16* __restrict__ wtl,
              const float* __restrict__ bias, float* __restrict__ out)
{
    __shared__ __align__(16) __bf16 SM[16384];
    __bf16* Ah = SM;
    __bf16* Al = SM + 4096;
    __bf16* Bh = SM + 8192;
    __bf16* Bl = SM + 12288;

    const int tid  = threadIdx.x;
    const int lane = tid & 63;
    const int wave = tid >> 6;
    const int quad = lane >> 4;
    const int m    = lane & 15;
    const int wr   = wave >> 1, wc = wave & 1;
    const int row0 = blockIdx.x * 128;
    const int col0 = blockIdx.y * 128;

    const size_t aoff0 = (size_t)(row0 + wave * 16 + m) * DM + (quad << 3);
    const size_t aoff1 = (size_t)(row0 + (wave + 4) * 16 + m) * DM + (quad << 3);
    const size_t boff0 = (size_t)(col0 + wave * 16 + m) * DM + (quad << 3);
    const size_t boff1 = (size_t)(col0 + (wave + 4) * 16 + m) * DM + (quad << 3);
    __bf16* lA0 = &Ah[wave << 9];       __bf16* lA1 = &Ah[(wave + 4) << 9];
    __bf16* lAl0 = &Al[wave << 9];      __bf16* lAl1 = &Al[(wave + 4) << 9];
    __bf16* lB0 = &Bh[wave << 9];       __bf16* lB1 = &Bh[(wave + 4) << 9];
    __bf16* lBl0 = &Bl[wave << 9];      __bf16* lBl1 = &Bl[(wave + 4) << 9];

    f32x4 acc[4][4];
#pragma unroll
    for (int i = 0; i < 4; ++i)
#pragma unroll
        for (int j = 0; j < 4; ++j) acc[i][j] = (f32x4){0.f, 0.f, 0.f, 0.f};

    for (int k0 = 0; k0 < DM; k0 += 32) {
        async16(ah + aoff0 + k0, lA0);
        async16(ah + aoff1 + k0, lA1);
        async16(al_ + aoff0 + k0, lAl0);
        async16(al_ + aoff1 + k0, lAl1);
        async16(wth + boff0 + k0, lB0);
        async16(wth + boff1 + k0, lB1);
        async16(wtl + boff0 + k0, lBl0);
        async16(wtl + boff1 + k0, lBl1);
        __syncthreads();

        bf16x8 avh[4], avl[4], bvh[4], bvl[4];
#pragma unroll
        for (int t = 0; t < 4; ++t) {
            int ai  = ((((wr << 2) + t) << 6) + lane) << 3;
            int bi2 = ((((wc << 2) + t) << 6) + lane) << 3;
            avh[t] = *(const bf16x8*)&Ah[ai];
            avl[t] = *(const bf16x8*)&Al[ai];
            bvh[t] = *(const bf16x8*)&Bh[bi2];
            bvl[t] = *(const bf16x8*)&Bl[bi2];
        }
#pragma unroll
        for (int rt = 0; rt < 4; ++rt)
#pragma unroll
            for (int ct = 0; ct < 4; ++ct) {
                acc[rt][ct] = MFMA16(avh[rt], bvl[ct], acc[rt][ct]);
                acc[rt][ct] = MFMA16(avl[rt], bvh[ct], acc[rt][ct]);
                acc[rt][ct] = MFMA16(avh[rt], bvh[ct], acc[rt][ct]);
            }
        __syncthreads();
    }

    // epilogue: LDS transpose -> coalesced float4 stores
    const int row0w = row0 + wr * 64;
    const int colw  = col0 + wc * 64;
    float bc[4];
#pragma unroll
    for (int ct = 0; ct < 4; ++ct) bc[ct] = bias[colw + (ct << 4) + m];

    float* tb = (float*)SM + wave * 1088;
    const int rr = lane >> 2, jj = lane & 3;
#pragma unroll
    for (int rt = 0; rt < 4; ++rt) {
#pragma unroll
        for (int ct = 0; ct < 4; ++ct)
#pragma unroll
            for (int rg = 0; rg < 4; ++rg)
                tb[((quad << 2) + rg) * 68 + (ct << 4) + m] =
                    acc[rt][ct][rg] + bc[ct];
        LGKM0();
        int n = row0w + (rt << 4) + rr;
#pragma unroll
        for (int i = 0; i < 4; ++i) {
            int c = (jj << 2) + (i << 4);
            *(float4*)&out[(size_t)n * DM + colw + c] =
                *(const float4*)&tb[rr * 68 + c];
        }
    }
}

// ---------------------------------------------------------------------------
extern "C" void kernel_launch(void* const* d_in, const int* in_sizes, int n_in,
                              void* d_out, int out_size, void* d_ws, size_t ws_size,
                              hipStream_t stream)
{
    const float* x    = (const float*)d_in[0];
    const float* Wqkv = (const float*)d_in[1];
    const float* bqkv = (const float*)d_in[2];
    const float* Wo   = (const float*)d_in[3];
    const float* bo   = (const float*)d_in[4];
    float* out = (float*)d_out;

    char* ws = (char*)d_ws;
    const size_t MB = 1024 * 1024;
    __bf16* qhi   = (__bf16*)(ws);                         // 8 MB [B,H,S,64]
    __bf16* qlo   = (__bf16*)(ws + 8 * MB);                // 8 MB
    __bf16* xhi   = (__bf16*)(ws + 16 * MB);               // 8 MB (later: ohi)
    __bf16* xlo   = (__bf16*)(ws + 24 * MB);               // 8 MB (later: olo)
    __bf16* khi   = (__bf16*)(ws + 32 * MB);               // 8 MB [B,H,S,64]
    __bf16* klo   = (__bf16*)(ws + 40 * MB);               // 8 MB
    __bf16* vT    = (__bf16*)(ws + 48 * MB);               // 8 MB [B,H,64,S]
    __bf16* wqt_h = (__bf16*)(ws + 56 * MB);               // 1.5 MB [1536][512]
    __bf16* wqt_l = (__bf16*)(ws + 56 * MB + 1536 * 1024);
    __bf16* wot_h = (__bf16*)(ws + 59 * MB);               // 0.5 MB [512][512]
    __bf16* wot_l = (__bf16*)(ws + 59 * MB + 512 * 1024);
    float2* rtab  = (float2*)(ws + 60 * MB);               // 0.5 MB [2048][32]

    prep_rope<<<256, 256, 0, stream>>>(rtab);
    prep_tw<<<dim3(24, 8), 256, 0, stream>>>(Wqkv, wqt_h, wqt_l, 3 * DM);
    prep_tw<<<dim3(8, 8), 256, 0, stream>>>(Wo, wot_h, wot_l, DM);
    prep_x<<<2048, 256, 0, stream>>>(x, xhi, xlo);
    qkv_mfma<<<dim3(64, 12), 256, 0, stream>>>(xhi, xlo, wqt_h, wqt_l, bqkv,
                                               rtab, qhi, qlo, khi, klo, vT);
    attn_mfma<<<dim3(32, 32), 256, 0, stream>>>(qhi, qlo, khi, klo, vT,
                                                xhi, xlo);
    out_mfma<<<dim3(64, 4), 256, 0, stream>>>(xhi, xlo, wot_h, wot_l, bo, out);
}

// Round 6
// 279.691 us; speedup vs baseline: 1.3280x; 1.3280x over previous
//
#include <hip/hip_runtime.h>
#include <math.h>

// Problem constants: B=4, S=2048, D=512, H=8, Hd=64
#define SEQ 2048
#define DM 512
#define NH 8
#define HD 64

typedef __bf16 bf16x8 __attribute__((ext_vector_type(8)));
typedef __bf16 bf16x4 __attribute__((ext_vector_type(4)));
typedef float f32x4 __attribute__((ext_vector_type(4)));
#define MFMA16(A, B, C) __builtin_amdgcn_mfma_f32_16x16x32_bf16(A, B, C, 0, 0, 0)

__device__ __forceinline__ void async16(const void* g, void* l) {
    __builtin_amdgcn_global_load_lds((__attribute__((address_space(1))) void*)g,
                                     (__attribute__((address_space(3))) void*)l,
                                     16, 0, 0);
}
#define LGKM0() asm volatile("s_waitcnt lgkmcnt(0)" ::: "memory")

// scale = 1/sqrt(64) * log2(e), folded into q at the QKV epilogue
#define QSCALE 0.18033688011112042f

// ---------------------------------------------------------------------------
// Prep 1: RoPE table  tab[s][p] = (cos, sin)(s * 10000^(-p/32)), 2048x32
// ---------------------------------------------------------------------------
__global__ __launch_bounds__(256)
void prep_rope(float2* __restrict__ tab)
{
    int idx = blockIdx.x * 256 + threadIdx.x;   // 65536
    int s = idx >> 5, p = idx & 31;
    const float c = -0.28782313662425572f;      // -ln(10000)/32
    float f = (float)s * expf(c * (float)p);
    float sn, cs;
    sincosf(f, &sn, &cs);
    tab[idx] = make_float2(cs, sn);
}

// ---------------------------------------------------------------------------
// Prep 2: W [512][N] fp32 -> Wt hi/lo bf16 [N][512], via LDS tile transpose
// ---------------------------------------------------------------------------
__global__ __launch_bounds__(256)
void prep_tw(const float* __restrict__ W, __bf16* __restrict__ hi,
             __bf16* __restrict__ lo, int N)
{
    __shared__ float T[64][65];
    const int tid = threadIdx.x;
    const int c0 = blockIdx.x * 64, k0 = blockIdx.y * 64;
#pragma unroll
    for (int it = 0; it < 4; ++it) {
        int idx = it * 256 + tid;
        int r = idx >> 4, c4 = (idx & 15) << 2;
        *(float4*)&T[r][c4] = *(const float4*)&W[(size_t)(k0 + r) * N + c0 + c4];
    }
    __syncthreads();
#pragma unroll
    for (int it = 0; it < 4; ++it) {
        int idx = it * 256 + tid;
        int c = idx >> 4, k4 = (idx & 15) << 2;
        bf16x4 hv, lv;
#pragma unroll
        for (int r = 0; r < 4; ++r) {
            float w = T[k4 + r][c];
            __bf16 h = (__bf16)w;
            hv[r] = h;
            lv[r] = (__bf16)(w - (float)h);
        }
        size_t off = (size_t)(c0 + c) * DM + k0 + k4;
        *(bf16x4*)&hi[off] = hv;
        *(bf16x4*)&lo[off] = lv;
    }
}

// ---------------------------------------------------------------------------
// Prep 3: x fp32 -> xhi/xlo bf16 (row-major [8192][512])
// ---------------------------------------------------------------------------
__global__ __launch_bounds__(256)
void prep_x(const float* __restrict__ x, __bf16* __restrict__ xh,
            __bf16* __restrict__ xl)
{
    size_t i = ((size_t)blockIdx.x * 256 + threadIdx.x) << 3;
    float4 a0 = *(const float4*)&x[i];
    float4 a1 = *(const float4*)&x[i + 4];
    float fv[8] = {a0.x, a0.y, a0.z, a0.w, a1.x, a1.y, a1.z, a1.w};
    bf16x8 hv, lv;
#pragma unroll
    for (int j = 0; j < 8; ++j) {
        __bf16 h = (__bf16)fv[j];
        hv[j] = h;
        lv[j] = (__bf16)(fv[j] - (float)h);
    }
    *(bf16x8*)&xh[i] = hv;
    *(bf16x8*)&xl[i] = lv;
}

// ---------------------------------------------------------------------------
// Kernel 1: QKV GEMM, async-staged split-bf16 MFMA (128x128, 4 waves).
// q: PRE-SCALED (QSCALE) hi/lo bf16 [B,H,S,64]; k: hi/lo bf16 [B,H,S,64];
// v: bf16 transposed [B,H,64,S].
// ---------------------------------------------------------------------------
__global__ __launch_bounds__(256)
void qkv_mfma(const __bf16* __restrict__ xh, const __bf16* __restrict__ xl,
              const __bf16* __restrict__ wth, const __bf16* __restrict__ wtl,
              const float* __restrict__ bias, const float2* __restrict__ tab,
              __bf16* __restrict__ qho, __bf16* __restrict__ qlo_,
              __bf16* __restrict__ kho, __bf16* __restrict__ klo_,
              __bf16* __restrict__ vo)
{
    __shared__ __align__(16) __bf16 SM[16384];      // 32 KB
    __bf16* Ah = SM;
    __bf16* Al = SM + 4096;
    __bf16* Bh = SM + 8192;
    __bf16* Bl = SM + 12288;

    const int tid  = threadIdx.x;
    const int lane = tid & 63;
    const int wave = tid >> 6;
    const int quad = lane >> 4;
    const int m    = lane & 15;
    const int wr   = wave >> 1, wc = wave & 1;
    const int row0 = blockIdx.x * 128;
    const int by   = blockIdx.y;            // 0..11
    const int col0 = by * 128;

    const size_t aoff0 = (size_t)(row0 + wave * 16 + m) * DM + (quad << 3);
    const size_t aoff1 = (size_t)(row0 + (wave + 4) * 16 + m) * DM + (quad << 3);
    const size_t boff0 = (size_t)(col0 + wave * 16 + m) * DM + (quad << 3);
    const size_t boff1 = (size_t)(col0 + (wave + 4) * 16 + m) * DM + (quad << 3);
    __bf16* lA0 = &Ah[wave << 9];       __bf16* lA1 = &Ah[(wave + 4) << 9];
    __bf16* lAl0 = &Al[wave << 9];      __bf16* lAl1 = &Al[(wave + 4) << 9];
    __bf16* lB0 = &Bh[wave << 9];       __bf16* lB1 = &Bh[(wave + 4) << 9];
    __bf16* lBl0 = &Bl[wave << 9];      __bf16* lBl1 = &Bl[(wave + 4) << 9];

    f32x4 acc[4][4];
#pragma unroll
    for (int i = 0; i < 4; ++i)
#pragma unroll
        for (int j = 0; j < 4; ++j) acc[i][j] = (f32x4){0.f, 0.f, 0.f, 0.f};

    for (int k0 = 0; k0 < DM; k0 += 32) {
        async16(xh + aoff0 + k0, lA0);
        async16(xh + aoff1 + k0, lA1);
        async16(xl + aoff0 + k0, lAl0);
        async16(xl + aoff1 + k0, lAl1);
        async16(wth + boff0 + k0, lB0);
        async16(wth + boff1 + k0, lB1);
        async16(wtl + boff0 + k0, lBl0);
        async16(wtl + boff1 + k0, lBl1);
        __syncthreads();

        bf16x8 avh[4], avl[4], bvh[4], bvl[4];
#pragma unroll
        for (int t = 0; t < 4; ++t) {
            int ai  = ((((wr << 2) + t) << 6) + lane) << 3;
            int bi2 = ((((wc << 2) + t) << 6) + lane) << 3;
            avh[t] = *(const bf16x8*)&Ah[ai];
            avl[t] = *(const bf16x8*)&Al[ai];
            bvh[t] = *(const bf16x8*)&Bh[bi2];
            bvl[t] = *(const bf16x8*)&Bl[bi2];
        }
#pragma unroll
        for (int rt = 0; rt < 4; ++rt)
#pragma unroll
            for (int ct = 0; ct < 4; ++ct) {
                acc[rt][ct] = MFMA16(avh[rt], bvl[ct], acc[rt][ct]);
                acc[rt][ct] = MFMA16(avl[rt], bvh[ct], acc[rt][ct]);
                acc[rt][ct] = MFMA16(avh[rt], bvh[ct], acc[rt][ct]);
            }
        __syncthreads();
    }

    // ---- epilogue ----
    const int sel   = by >> 2;              // 0=q 1=k 2=v
    const int head  = ((by << 1) + wc) & 7;
    const int row0w = row0 + wr * 64;
    const int bidx  = row0w >> 11;
    const int s0    = row0w & (SEQ - 1);
    const int colw  = col0 + wc * 64;

    float bc[4];
#pragma unroll
    for (int ct = 0; ct < 4; ++ct) bc[ct] = bias[colw + (ct << 4) + m];

    if (sel == 2) {
        // v: direct transposed store [B,H,d,s], bf16x4 along s
#pragma unroll
        for (int ct = 0; ct < 4; ++ct) {
            int d = (ct << 4) + m;
#pragma unroll
            for (int rt = 0; rt < 4; ++rt) {
                f32x4 a = acc[rt][ct];
                bf16x4 ov;
#pragma unroll
                for (int rg = 0; rg < 4; ++rg) ov[rg] = (__bf16)(a[rg] + bc[ct]);
                size_t off = ((size_t)((bidx * NH + head) * HD + d)) * SEQ
                           + s0 + (rt << 4) + (quad << 2);
                *(bf16x4*)&vo[off] = ov;
            }
        }
    } else {
        // q/k: per-wave LDS transpose + RoPE + hi/lo bf16 vector stores
        const float sc = (sel == 0) ? QSCALE : 1.0f;
        __bf16* dh = (sel == 0) ? qho : kho;
        __bf16* dl = (sel == 0) ? qlo_ : klo_;
        float* tb = (float*)SM + wave * 1088;       // 16 x 68 f32
        const int rr = lane >> 2, jj = lane & 3;
#pragma unroll
        for (int rt = 0; rt < 4; ++rt) {
#pragma unroll
            for (int ct = 0; ct < 4; ++ct)
#pragma unroll
                for (int rg = 0; rg < 4; ++rg)
                    tb[((quad << 2) + rg) * 68 + (ct << 4) + m] =
                        acc[rt][ct][rg] + bc[ct];
            LGKM0();
            int s = (row0w + (rt << 4) + rr) & (SEQ - 1);
#pragma unroll
            for (int i = 0; i < 4; ++i) {
                int c = (jj << 2) + (i << 4);
                float4 vv = *(const float4*)&tb[rr * 68 + c];
                float4 t4 = *(const float4*)&tab[(s << 5) + (c >> 1)];
                float rv[4];
                rv[0] = (vv.x * t4.x - vv.y * t4.y) * sc;
                rv[1] = (vv.x * t4.y + vv.y * t4.x) * sc;
                rv[2] = (vv.z * t4.z - vv.w * t4.w) * sc;
                rv[3] = (vv.z * t4.w + vv.w * t4.z) * sc;
                size_t off = (((size_t)(bidx * NH + head) * SEQ + s) << 6) + c;
                bf16x4 hv, lv;
#pragma unroll
                for (int j = 0; j < 4; ++j) {
                    __bf16 h = (__bf16)rv[j];
                    hv[j] = h;
                    lv[j] = (__bf16)(rv[j] - (float)h);
                }
                *(bf16x4*)&dh[off] = hv;
                *(bf16x4*)&dl[off] = lv;
            }
        }
    }
}

// ---------------------------------------------------------------------------
// Kernel 2: MFMA flash attention, q-split, 128 q-rows per block (32 q/wave).
// Block-wide staged K/V (64-key tiles, 2-barrier m97-style loop). Each wave
// computes S^T = K.Q^T for its 32 q (2 q-groups) REUSING the same K-frag LDS
// reads, then O += P.V reusing the same V-frag reads. Per-lane softmax state
// (q = m), register P round-trip via per-wave LDS. Output pre-split hi/lo.
// ---------------------------------------------------------------------------
__global__ __launch_bounds__(256, 2)
void attn_mfma(const __bf16* __restrict__ qhi, const __bf16* __restrict__ qlo,
               const __bf16* __restrict__ khi, const __bf16* __restrict__ klo,
               const __bf16* __restrict__ vt,
               __bf16* __restrict__ oh, __bf16* __restrict__ ol)
{
    __shared__ __align__(16) __bf16 KH[4096];
    __shared__ __align__(16) __bf16 KL[4096];
    __shared__ __align__(16) __bf16 VF[4096];
    __shared__ __align__(16) __bf16 PW[4][2304];   // per wave: 32 rows x 72

    const int tid  = threadIdx.x;
    const int lane = tid & 63;
    const int wave = tid >> 6;
    const int m    = lane & 15;
    const int quad = lane >> 4;

    const int bh = blockIdx.y;      // 0..31
    const int qt = blockIdx.x;      // 0..15
    const int bi = bh >> 3, h = bh & 7;

    const __bf16* qhp = qhi + ((size_t)bh * SEQ + qt * 128 + wave * 32) * HD;
    const __bf16* qlp = qlo + ((size_t)bh * SEQ + qt * 128 + wave * 32) * HD;
    const __bf16* khp = khi + (size_t)bh * SEQ * HD;
    const __bf16* klp = klo + (size_t)bh * SEQ * HD;
    const __bf16* vp  = vt  + (size_t)bh * HD * SEQ;

    // Q B-frags (pre-scaled, pre-split): B[k=d=c*32+quad*8+j][n=q=qg*16+m]
    bf16x8 qh[2][2], ql[2][2];
#pragma unroll
    for (int qg = 0; qg < 2; ++qg)
#pragma unroll
        for (int c = 0; c < 2; ++c) {
            size_t off = ((size_t)(qg * 16 + m) << 6) + c * 32 + (quad << 3);
            qh[qg][c] = *(const bf16x8*)&qhp[off];
            ql[qg][c] = *(const bf16x8*)&qlp[off];
        }

    f32x4 oacc[2][4];   // [qg][dt]: D[q=quad*4+rg (+qg*16)][d=dt*16+m]
#pragma unroll
    for (int qg = 0; qg < 2; ++qg)
#pragma unroll
        for (int dt = 0; dt < 4; ++dt) oacc[qg][dt] = (f32x4){0.f, 0.f, 0.f, 0.f};
    float mrow[2] = {-1e30f, -1e30f};
    float lrow[2] = {0.f, 0.f};

    // block-wide staging: wave stages keys wave*16+m (c=0,1); V rows d=wave*16+m
    const size_t koff0 = ((size_t)(wave * 16 + m) << 6) + (quad << 3);
    const size_t koff1 = koff0 + 32;
    const size_t voff0 = ((size_t)(wave * 16 + m) << 11) + (quad << 3);
    const size_t voff1 = voff0 + 32;
    __bf16* lkh0 = &KH[wave << 9];   __bf16* lkh1 = &KH[(wave + 4) << 9];
    __bf16* lkl0 = &KL[wave << 9];   __bf16* lkl1 = &KL[(wave + 4) << 9];
    __bf16* lvf0 = &VF[wave << 9];   __bf16* lvf1 = &VF[(wave + 4) << 9];

    for (int kt = 0; kt < SEQ / 64; ++kt) {
        __syncthreads();   // prior tile's frag reads complete
        async16(khp + koff0 + ((size_t)kt << 12), lkh0);
        async16(khp + koff1 + ((size_t)kt << 12), lkh1);
        async16(klp + koff0 + ((size_t)kt << 12), lkl0);
        async16(klp + koff1 + ((size_t)kt << 12), lkl1);
        async16(vp + voff0 + ((size_t)kt << 6), lvf0);
        async16(vp + voff1 + ((size_t)kt << 6), lvf1);
        __syncthreads();   // copies landed

        // ---- S^T = K·Q^T : [64 keys][32 q], K-frags loaded once per nt ----
        f32x4 sv[4][2];
#pragma unroll
        for (int nt = 0; nt < 4; ++nt) {
            bf16x8 kh[2], kl[2];
#pragma unroll
            for (int c = 0; c < 2; ++c) {
                kh[c] = *(const bf16x8*)&KH[((c * 4 + nt) * 64 + lane) << 3];
                kl[c] = *(const bf16x8*)&KL[((c * 4 + nt) * 64 + lane) << 3];
            }
#pragma unroll
            for (int qg = 0; qg < 2; ++qg) {
                f32x4 s = (f32x4){0.f, 0.f, 0.f, 0.f};
#pragma unroll
                for (int c = 0; c < 2; ++c) {
                    s = MFMA16(kh[c], ql[qg][c], s);
                    s = MFMA16(kl[c], qh[qg][c], s);
                    s = MFMA16(kh[c], qh[qg][c], s);
                }
                sv[nt][qg] = s;   // [key=nt*16+quad*4+rg][q=qg*16+m]
            }
        }

        // ---- online softmax (per-lane q = qg*16+m), log2 domain ----
        float alpha[2];
#pragma unroll
        for (int qg = 0; qg < 2; ++qg) {
            float t = fmaxf(fmaxf(fmaxf(sv[0][qg][0], sv[0][qg][1]),
                                  fmaxf(sv[0][qg][2], sv[0][qg][3])),
                            fmaxf(fmaxf(sv[1][qg][0], sv[1][qg][1]),
                                  fmaxf(sv[1][qg][2], sv[1][qg][3])));
            float u = fmaxf(fmaxf(fmaxf(sv[2][qg][0], sv[2][qg][1]),
                                  fmaxf(sv[2][qg][2], sv[2][qg][3])),
                            fmaxf(fmaxf(sv[3][qg][0], sv[3][qg][1]),
                                  fmaxf(sv[3][qg][2], sv[3][qg][3])));
            t = fmaxf(t, u);
            t = fmaxf(t, __shfl_xor(t, 16));
            t = fmaxf(t, __shfl_xor(t, 32));
            float mn = fmaxf(mrow[qg], t);
            alpha[qg] = exp2f(mrow[qg] - mn);
            mrow[qg] = mn;
            float rs = 0.f;
#pragma unroll
            for (int nt = 0; nt < 4; ++nt)
#pragma unroll
                for (int rg = 0; rg < 4; ++rg) {
                    float p = exp2f(sv[nt][qg][rg] - mn);
                    sv[nt][qg][rg] = p;
                    rs += p;
                }
            rs += __shfl_xor(rs, 16);
            rs += __shfl_xor(rs, 32);
            lrow[qg] = lrow[qg] * alpha[qg] + rs;
        }
        // O-rescale: alpha redistributed to C-layout rows
#pragma unroll
        for (int qg = 0; qg < 2; ++qg) {
#pragma unroll
            for (int rg = 0; rg < 4; ++rg) {
                float a = __shfl(alpha[qg], (quad << 2) + rg, 16);
#pragma unroll
                for (int dt = 0; dt < 4; ++dt) oacc[qg][dt][rg] *= a;
            }
        }

        // ---- P (C-layout) -> A-frag via per-wave LDS, bf16x4 stores ----
        __bf16* pw = PW[wave];
#pragma unroll
        for (int nt = 0; nt < 4; ++nt)
#pragma unroll
            for (int qg = 0; qg < 2; ++qg) {
                bf16x4 p4;
#pragma unroll
                for (int rg = 0; rg < 4; ++rg) p4[rg] = (__bf16)sv[nt][qg][rg];
                *(bf16x4*)&pw[(qg * 16 + m) * 72 + (nt << 4) + (quad << 2)] = p4;
            }
        LGKM0();
        bf16x8 pf[2][2];
#pragma unroll
        for (int qg = 0; qg < 2; ++qg)
#pragma unroll
            for (int c = 0; c < 2; ++c)
                pf[qg][c] = *(const bf16x8*)&pw[(qg * 16 + m) * 72 + c * 32
                                                + (quad << 3)];

        // ---- O += P·V : V-frags loaded once per dt, reused across qg ----
#pragma unroll
        for (int dt = 0; dt < 4; ++dt) {
            bf16x8 v0 = *(const bf16x8*)&VF[((0 * 4 + dt) * 64 + lane) << 3];
            bf16x8 v1 = *(const bf16x8*)&VF[((1 * 4 + dt) * 64 + lane) << 3];
#pragma unroll
            for (int qg = 0; qg < 2; ++qg) {
                oacc[qg][dt] = MFMA16(pf[qg][0], v0, oacc[qg][dt]);
                oacc[qg][dt] = MFMA16(pf[qg][1], v1, oacc[qg][dt]);
            }
        }
    }

    // ---- epilogue: normalize, split hi/lo, write [B,S,512] ----
#pragma unroll
    for (int qg = 0; qg < 2; ++qg) {
        float inv = 1.0f / lrow[qg];
        size_t ob = ((size_t)(bi * SEQ + qt * 128 + wave * 32 + qg * 16
                              + (quad << 2))) * DM + h * HD + m;
#pragma unroll
        for (int rg = 0; rg < 4; ++rg) {
            float il = __shfl(inv, (quad << 2) + rg, 16);
#pragma unroll
            for (int dt = 0; dt < 4; ++dt) {
                float val = oacc[qg][dt][rg] * il;
                __bf16 hv = (__bf16)val;
                oh[ob + (size_t)rg * DM + dt * 16] = hv;
                ol[ob + (size_t)rg * DM + dt * 16] = (__bf16)(val - (float)hv);
            }
        }
    }
}

// ---------------------------------------------------------------------------
// Kernel 3: out = attn @ Wo + bo, async-staged split-bf16 MFMA (128x128).
// ---------------------------------------------------------------------------
__global__ __launch_bounds__(256)
void out_mfma(const __bf16* __restrict__ ah, const __bf16* __restrict__ al_,
              const __bf16* __restrict__ wth, const __bf16* __restrict__ wtl,
              const float* __restrict__ bias, float* __restrict__ out)
{
    __shared__ __align__(16) __bf16 SM[16384];
    __bf16* Ah = SM;
    __bf16* Al = SM + 4096;
    __bf16* Bh = SM + 8192;
    __bf16* Bl = SM + 12288;

    const int tid  = threadIdx.x;
    const int lane = tid & 63;
    const int wave = tid >> 6;
    const int quad = lane >> 4;
    const int m    = lane & 15;
    const int wr   = wave >> 1, wc = wave & 1;
    const int row0 = blockIdx.x * 128;
    const int col0 = blockIdx.y * 128;

    const size_t aoff0 = (size_t)(row0 + wave * 16 + m) * DM + (quad << 3);
    const size_t aoff1 = (size_t)(row0 + (wave + 4) * 16 + m) * DM + (quad << 3);
    const size_t boff0 = (size_t)(col0 + wave * 16 + m) * DM + (quad << 3);
    const size_t boff1 = (size_t)(col0 + (wave + 4) * 16 + m) * DM + (quad << 3);
    __bf16* lA0 = &Ah[wave << 9];       __bf16* lA1 = &Ah[(wave + 4) << 9];
    __bf16* lAl0 = &Al[wave << 9];      __bf16* lAl1 = &Al[(wave + 4) << 9];
    __bf16* lB0 = &Bh[wave << 9];       __bf16* lB1 = &Bh[(wave + 4) << 9];
    __bf16* lBl0 = &Bl[wave << 9];      __bf16* lBl1 = &Bl[(wave + 4) << 9];

    f32x4 acc[4][4];
#pragma unroll
    for (int i = 0; i < 4; ++i)
#pragma unroll
        for (int j = 0; j < 4; ++j) acc[i][j] = (f32x4){0.f, 0.f, 0.f, 0.f};

    for (int k0 = 0; k0 < DM; k0 += 32) {
        async16(ah + aoff0 + k0, lA0);
        async16(ah + aoff1 + k0, lA1);
        async16(al_ + aoff0 + k0, lAl0);
        async16(al_ + aoff1 + k0, lAl1);
        async16(wth + boff0 + k0, lB0);
        async16(wth + boff1 + k0, lB1);
        async16(wtl + boff0 + k0, lBl0);
        async16(wtl + boff1 + k0, lBl1);
        __syncthreads();

        bf16x8 avh[4], avl[4], bvh[4], bvl[4];
#pragma unroll
        for (int t = 0; t < 4; ++t) {
            int ai  = ((((wr << 2) + t) << 6) + lane) << 3;
            int bi2 = ((((wc << 2) + t) << 6) + lane) << 3;
            avh[t] = *(const bf16x8*)&Ah[ai];
            avl[t] = *(const bf16x8*)&Al[ai];
            bvh[t] = *(const bf16x8*)&Bh[bi2];
            bvl[t] = *(const bf16x8*)&Bl[bi2];
        }
#pragma unroll
        for (int rt = 0; rt < 4; ++rt)
#pragma unroll
            for (int ct = 0; ct < 4; ++ct) {
                acc[rt][ct] = MFMA16(avh[rt], bvl[ct], acc[rt][ct]);
                acc[rt][ct] = MFMA16(avl[rt], bvh[ct], acc[rt][ct]);
                acc[rt][ct] = MFMA16(avh[rt], bvh[ct], acc[rt][ct]);
            }
        __syncthreads();
    }

    // epilogue: LDS transpose -> coalesced float4 stores
    const int row0w = row0 + wr * 64;
    const int colw  = col0 + wc * 64;
    float bc[4];
#pragma unroll
    for (int ct = 0; ct < 4; ++ct) bc[ct] = bias[colw + (ct << 4) + m];

    float* tb = (float*)SM + wave * 1088;
    const int rr = lane >> 2, jj = lane & 3;
#pragma unroll
    for (int rt = 0; rt < 4; ++rt) {
#pragma unroll
        for (int ct = 0; ct < 4; ++ct)
#pragma unroll
            for (int rg = 0; rg < 4; ++rg)
                tb[((quad << 2) + rg) * 68 + (ct << 4) + m] =
                    acc[rt][ct][rg] + bc[ct];
        LGKM0();
        int n = row0w + (rt << 4) + rr;
#pragma unroll
        for (int i = 0; i < 4; ++i) {
            int c = (jj << 2) + (i << 4);
            *(float4*)&out[(size_t)n * DM + colw + c] =
                *(const float4*)&tb[rr * 68 + c];
        }
    }
}

// ---------------------------------------------------------------------------
extern "C" void kernel_launch(void* const* d_in, const int* in_sizes, int n_in,
                              void* d_out, int out_size, void* d_ws, size_t ws_size,
                              hipStream_t stream)
{
    const float* x    = (const float*)d_in[0];
    const float* Wqkv = (const float*)d_in[1];
    const float* bqkv = (const float*)d_in[2];
    const float* Wo   = (const float*)d_in[3];
    const float* bo   = (const float*)d_in[4];
    float* out = (float*)d_out;

    char* ws = (char*)d_ws;
    const size_t MB = 1024 * 1024;
    __bf16* qhi   = (__bf16*)(ws);                         // 8 MB [B,H,S,64]
    __bf16* qlo   = (__bf16*)(ws + 8 * MB);                // 8 MB
    __bf16* xhi   = (__bf16*)(ws + 16 * MB);               // 8 MB (later: ohi)
    __bf16* xlo   = (__bf16*)(ws + 24 * MB);               // 8 MB (later: olo)
    __bf16* khi   = (__bf16*)(ws + 32 * MB);               // 8 MB [B,H,S,64]
    __bf16* klo   = (__bf16*)(ws + 40 * MB);               // 8 MB
    __bf16* vT    = (__bf16*)(ws + 48 * MB);               // 8 MB [B,H,64,S]
    __bf16* wqt_h = (__bf16*)(ws + 56 * MB);               // 1.5 MB [1536][512]
    __bf16* wqt_l = (__bf16*)(ws + 56 * MB + 1536 * 1024);
    __bf16* wot_h = (__bf16*)(ws + 59 * MB);               // 0.5 MB [512][512]
    __bf16* wot_l = (__bf16*)(ws + 59 * MB + 512 * 1024);
    float2* rtab  = (float2*)(ws + 60 * MB);               // 0.5 MB [2048][32]

    prep_rope<<<256, 256, 0, stream>>>(rtab);
    prep_tw<<<dim3(24, 8), 256, 0, stream>>>(Wqkv, wqt_h, wqt_l, 3 * DM);
    prep_tw<<<dim3(8, 8), 256, 0, stream>>>(Wo, wot_h, wot_l, DM);
    prep_x<<<2048, 256, 0, stream>>>(x, xhi, xlo);
    qkv_mfma<<<dim3(64, 12), 256, 0, stream>>>(xhi, xlo, wqt_h, wqt_l, bqkv,
                                               rtab, qhi, qlo, khi, klo, vT);
    attn_mfma<<<dim3(16, 32), 256, 0, stream>>>(qhi, qlo, khi, klo, vT,
                                                xhi, xlo);
    out_mfma<<<dim3(64, 4), 256, 0, stream>>>(xhi, xlo, wot_h, wot_l, bo, out);
}